// Round 8
// baseline (74.557 us; speedup 1.0000x reference)
//
#include <hip/hip_runtime.h>
#include <math.h>

#define HIN 32
#define WIN 32
#define NITER 3
#define TIN_ELEMS 131072  // 2*32*32*64

// ---------------- prep: input transpose + weight permute ----------------
// blocks 0..63: (n,c,y,x) -> (n,y,x,c) transpose of input
// block 64:     weight -> flipped+swizzled wprep[tap][g][(m+g)&7][l] (stride 64)
__global__ __launch_bounds__(256) void prep(const float* __restrict__ in,
                                            const float* __restrict__ weight,
                                            float* __restrict__ tin,
                                            float* __restrict__ wprep) {
    __shared__ float lds[64 * 33];
    const int b = blockIdx.x;
    const int t = threadIdx.x;
    if (b < 64) {
        const int n = b >> 5;
        const int s0 = (b & 31) << 5;  // spatial tile base (y*32+x), 32 wide
        const float* ib = in + n * 65536;
        float* ob = tin + n * 65536;
#pragma unroll
        for (int k = 0; k < 8; ++k) {
            int idx = k * 256 + t;
            int c = idx >> 5, sl = idx & 31;
            lds[c * 33 + sl] = ib[c * 1024 + s0 + sl];  // 128B coalesced runs
        }
        __syncthreads();
#pragma unroll
        for (int k = 0; k < 8; ++k) {
            int idx = k * 256 + t;
            int sl = idx >> 6, c = idx & 63;
            ob[(size_t)(s0 + sl) * 64 + c] = lds[c * 33 + sl];  // 256B coalesced
        }
    } else {
        // 512 (l,g,m) rows x 9 taps; pure shift/mask decode, taps unrolled
#pragma unroll
        for (int k = 0; k < 2; ++k) {
            const int lgm = k * 256 + t;
            const int l = lgm >> 6, g = (lgm >> 3) & 7, m = lgm & 7;
            const float* src = weight + lgm * 9;  // weight[l][g][m][kh][kw]
            float* drow = wprep + g * 64 + ((m + g) & 7) * 8 + l;
#pragma unroll
            for (int kh = 0; kh < 3; ++kh)
#pragma unroll
                for (int kw = 0; kw < 3; ++kw) {
                    const int tap = (2 - kh) * 3 + (2 - kw);  // flip
                    drow[tap * 512] = src[kh * 3 + kw];
                }
        }
    }
}

// ---- 8-lane sum entirely on the VALU pipe (DPP), no ds_swizzle ----
template <int CTRL>
__device__ __forceinline__ float dpp_add(float v) {
    int p = __builtin_amdgcn_update_dpp(0, __float_as_int(v), CTRL, 0xF, 0xF, true);
    return v + __int_as_float(p);
}
__device__ __forceinline__ float sum8(float v) {
    v = dpp_add<0xB1>(v);   // quad_perm [1,0,3,2]  = xor 1
    v = dpp_add<0x4E>(v);   // quad_perm [2,3,0,1]  = xor 2
    v = dpp_add<0x141>(v);  // row_half_mirror      = cross-quad in 8-group
    return v;
}

// ---------------- routing ----------------
// Parity path (TH,TW): T = TH*TW taps used; the other 72-8T votes are exactly
// zero -> contribute Z = 72-8T to the softmax denominator (shift-free softmax:
// bounded logits). normalize() is scale-invariant, so iterations carry the
// UNNORMALIZED weighted sums r[]; the single rcp(r8+Z) applies at the end.
// Weight staging: wave v copies pre-permuted tap v (2 coalesced float4 loads +
// 2 ds_write_b128 per lane, 1KB/inst). R5 lesson: 1 position/wave, pri<=32 VGPR.
template <int TH, int TW>
__device__ __forceinline__ void run_path(
    const float* __restrict__ tin, const float* __restrict__ wprep,
    const float* __restrict__ bias, float* __restrict__ out,
    float* __restrict__ wlds, float* __restrict__ olds,
    int t, int n, int p, int qb) {
    constexpr int T = TH * TW;
    constexpr float Z = (float)(72 - 8 * T);

    const int wave = t >> 6;
    const int lane = t & 63;

    // ---- stage T taps (pre-permuted, contiguous) ----
    if (wave < T) {
        const int hh = (TH == 1) ? 1 : ((TW == 2 ? (wave >> 1) : wave) * 2);
        const int ww = (TW == 1) ? 1 : ((wave & 1) * 2);
        const float4* src = (const float4*)(wprep + (hh * 3 + ww) * 512 + lane * 8);
        float4 a = src[0], b2 = src[1];
        float4* dst = (float4*)(wlds + wave * 512 + lane * 8);
        dst[0] = a;
        dst[1] = b2;
    }
    __syncthreads();

    const int g = lane >> 3;
    const int s = lane & 7;
    const int q = qb + 2 * wave;

    // ---- priors ----
    float pri[T][8];
#pragma unroll
    for (int i = 0; i < TH; ++i) {
        const int h = (TH == 1) ? 1 : i * 2;
        const int y = (p + h - 1) >> 1;
#pragma unroll
        for (int j = 0; j < TW; ++j) {
            const int v = i * TW + j;
            const int w = (TW == 1) ? 1 : j * 2;
            const int x = (q + w - 1) >> 1;
            const bool valid = (y < HIN) && (x < WIN);
            if (valid) {  // block-uniform path, wave-uniform validity
                float xv[8];
                const float4* xp =
                    (const float4*)(tin + (((size_t)n * HIN + y) * WIN + x) * 64 + s * 8);
                float4 x0 = xp[0], x1 = xp[1];
                xv[0] = x0.x; xv[1] = x0.y; xv[2] = x0.z; xv[3] = x0.w;
                xv[4] = x1.x; xv[5] = x1.y; xv[6] = x1.z; xv[7] = x1.w;
                const float* wb = wlds + (v * 8 + g) * 64;
#pragma unroll
                for (int m = 0; m < 8; ++m) {
                    const float4* wp = (const float4*)(wb + ((m + g) & 7) * 8);
                    float4 w0 = wp[0], w1 = wp[1];
                    pri[v][m] = xv[0] * w0.x + xv[1] * w0.y + xv[2] * w0.z + xv[3] * w0.w +
                                xv[4] * w1.x + xv[5] * w1.y + xv[6] * w1.z + xv[7] * w1.w;
                }
            } else {
#pragma unroll
                for (int m = 0; m < 8; ++m) pri[v][m] = 0.f;
            }
        }
    }

    // ---- r = unnormalized routing state (init: sum of votes) ----
    float r[9];
#pragma unroll
    for (int m = 0; m < 8; ++m) {
        float a = 0.f;
#pragma unroll
        for (int v = 0; v < T; ++v) a += pri[v][m];
        r[m] = sum8(a);
    }
    r[8] = (float)T * 8.f;  // placeholder; only last iteration's r[8] is used

#pragma unroll
    for (int it = 0; it < NITER; ++it) {
        float sn = 0.f;
#pragma unroll
        for (int m = 0; m < 8; ++m) sn += r[m] * r[m];
        const float inv = __builtin_amdgcn_rsqf(fmaxf(sn, 1e-24f));
        float on[8];
#pragma unroll
        for (int m = 0; m < 8; ++m) on[m] = r[m] * inv;

        float acc[9];  // acc[0..7] numerators, acc[8] = exp-sum
        acc[8] = 0.f;
        float e[T];
#pragma unroll
        for (int v = 0; v < T; ++v) {
            float a = 0.f;
#pragma unroll
            for (int m = 0; m < 8; ++m) a += pri[v][m] * on[m];
            e[v] = __expf(a);
            acc[8] += e[v];
        }
#pragma unroll
        for (int m = 0; m < 8; ++m) {
            float a = 0.f;
#pragma unroll
            for (int v = 0; v < T; ++v) a += e[v] * pri[v][m];
            acc[m] = a;
        }
#pragma unroll
        for (int j = 0; j < 9; ++j) r[j] = sum8(acc[j]);
    }

    // ---- apply the deferred softmax denominator, squash, emit ----
    const float invs = __builtin_amdgcn_rcpf(r[8] + Z);  // zero votes: exp(0)=1
    float o[8];
#pragma unroll
    for (int m = 0; m < 8; ++m) o[m] = r[m] * invs;

    float sn = 0.f;
#pragma unroll
    for (int m = 0; m < 8; ++m) sn += o[m] * o[m];
    const float factor =
        sn * __builtin_amdgcn_rcpf(1.f + sn) * __builtin_amdgcn_rsqf(sn + 1e-12f);

    float val = o[0];
#pragma unroll
    for (int m = 1; m < 8; ++m)
        if (s == m) val = o[m];
    val = val * factor + bias[g * 8 + s];

    olds[lane * 5 + wave] = val;

    __syncthreads();
    // store: c2 = t>>2 (channel), w = t&3 -> q = qb + 2w (stride-2, same parity)
    const int c2 = t >> 2, w = t & 3;
    out[(((size_t)n * 64 + c2) * 64 + p) * 64 + qb + 2 * w] = olds[c2 * 5 + w];
}

__global__ __launch_bounds__(256) void caps_routing(
    const float* __restrict__ tin, const float* __restrict__ wprep,
    const float* __restrict__ bias, float* __restrict__ out) {
    __shared__ float wlds[4 * 512];  // up to 4 staged taps, stride-64 rows
    __shared__ float olds[64 * 5];   // output staging
    const int t = threadIdx.x;

    // parity-grouped positions: all 4 waves of a block share (p&1, q&1)
    // b = n*1024 + p*16 + j ; j: qpar = j>>3, qb = (j&7)*8 + qpar
    const int b = blockIdx.x;
    const int n = b >> 10;
    const int p = (b >> 4) & 63;
    const int j = b & 15;
    const int qpar = j >> 3;
    const int qb = (j & 7) * 8 + qpar;

    if (p & 1) {
        if (qpar)
            run_path<2, 2>(tin, wprep, bias, out, wlds, olds, t, n, p, qb);
        else
            run_path<2, 1>(tin, wprep, bias, out, wlds, olds, t, n, p, qb);
    } else {
        if (qpar)
            run_path<1, 2>(tin, wprep, bias, out, wlds, olds, t, n, p, qb);
        else
            run_path<1, 1>(tin, wprep, bias, out, wlds, olds, t, n, p, qb);
    }
}

extern "C" void kernel_launch(void* const* d_in, const int* in_sizes, int n_in,
                              void* d_out, int out_size, void* d_ws, size_t ws_size,
                              hipStream_t stream) {
    const float* in = (const float*)d_in[0];
    const float* weight = (const float*)d_in[1];
    const float* bias = (const float*)d_in[2];
    float* out = (float*)d_out;
    float* tin = (float*)d_ws;
    float* wprep = (float*)d_ws + TIN_ELEMS;

    prep<<<65, 256, 0, stream>>>(in, weight, tin, wprep);
    caps_routing<<<2048, 256, 0, stream>>>(tin, wprep, bias, out);
}